// Round 3
// baseline (1090.836 us; speedup 1.0000x reference)
//
#include <hip/hip_runtime.h>

namespace {

typedef float v2f __attribute__((ext_vector_type(2)));

constexpr int T_SEQ = 2048;
constexpr int B_SZ  = 512;
constexpr int C_IN  = 8;
constexpr int H_SZ  = 20;
constexpr int P_LEN = 16;                 // steps per phase (barrier period)
constexpr int N_PH  = T_SEQ / P_LEN;      // 128 phases
constexpr int RING  = 2 * P_LEN;          // 32-slot rings (2 phases)
constexpr float LOG2E = 1.44269504088896340736f;

__device__ __forceinline__ float rlane(float v, int lane) {
  return __int_as_float(__builtin_amdgcn_readlane(__float_as_int(v), lane));
}

template<int S>
__device__ __forceinline__ float quad_bcast(float v) {
  return __int_as_float(__builtin_amdgcn_update_dpp(
      __float_as_int(v), __float_as_int(v), S * 0x55, 0xF, 0xF, true));
}

__device__ __forceinline__ v2f fma2(v2f a, v2f b, v2f c) {
  return __builtin_elementwise_fma(a, b, c);   // -> v_pk_fma_f32
}
__device__ __forceinline__ v2f splat2(float s) { v2f r; r.x = s; r.y = s; return r; }
__device__ __forceinline__ v2f zero2() { v2f r; r.x = 0.f; r.y = 0.f; return r; }

// Elementwise activation on both gate sets: sigmoid (g!=2) / tanh (g==2).
__device__ __forceinline__ v2f act2(v2f a, float cm, float am, float ad) {
  float ex = __builtin_amdgcn_exp2f(a.x * cm);
  float ey = __builtin_amdgcn_exp2f(a.y * cm);
  float sx = __builtin_amdgcn_rcpf(1.0f + ex);
  float sy = __builtin_amdgcn_rcpf(1.0f + ey);
  v2f r; r.x = __fmaf_rn(sx, am, ad); r.y = __fmaf_rn(sy, am, ad);
  return r;
}

__device__ __forceinline__ float fast_tanh(float a) {
  float e = __builtin_amdgcn_exp2f(a * (-2.0f * LOG2E));
  float s = __builtin_amdgcn_rcpf(1.0f + e);
  return __fmaf_rn(s, 2.0f, -1.0f);
}

// h[k] broadcast from lane-distributed regs (set1 at lanes 4k, k<16;
// set2 value for k=16..19 at lanes 4*(k-16)).  Round-0 inline form:
// rlane result feeds pk_fma directly (SGPR fold), no intermediate array.
#define H_BCAST(ha, hb, k) (((k) < 16) ? rlane((ha), 4 * (k)) : rlane((hb), 4 * ((k) - 16)))

__global__ __attribute__((amdgpu_flat_work_group_size(192, 192),
                          amdgpu_waves_per_eu(1, 1)))
void lstm2_3w(const float* __restrict__ x,
              const float* __restrict__ Wih0, const float* __restrict__ Whh0,
              const float* __restrict__ bih0, const float* __restrict__ bhh0,
              const float* __restrict__ Wih1, const float* __restrict__ Whh1,
              const float* __restrict__ bih1, const float* __restrict__ bhh1,
              float* __restrict__ out)
{
  // h0 handoff ring: 32 steps, 20 floats/slot (L0 writes, feeder reads).
  __shared__ __align__(16) float hbuf[RING][H_SZ];
  // Per-lane v2f y-dot partials (feeder writes, L1 reads). 16 KB.
  __shared__ __align__(16) v2f   ybuf[RING][64];
  // Per-lane v2f x-dot partials (feeder writes, L0 reads). 16 KB.
  __shared__ __align__(16) v2f   xsbuf[RING][64];
  // x broadcast staging, feeder-private, single buffer (within-superstep use).
  __shared__ __align__(16) float xbuf[P_LEN * C_IN];

  const int tid = threadIdx.x;
  const int wv  = tid >> 6;          // 0 = layer-0, 1 = feeder, 2 = layer-1
  const int l   = tid & 63;
  const int b   = blockIdx.x;
  const int k1  = l >> 2;            // 0..15
  const int g   = l & 3;             // gate slot: 0=i 1=f 2=g 3=o
  const int k2  = 16 + (k1 & 3);     // 16..19 (replicated)
  const int j1  = g * H_SZ + k1;
  const int j2  = g * H_SZ + k2;

  const bool  isg = (g == 2);
  const float cm  = isg ? (-2.0f * LOG2E) : (-LOG2E);
  const float am  = isg ?  2.0f : 1.0f;
  const float ad  = isg ? -1.0f : 0.0f;

  if (wv == 0) {
    // ================= layer-0 recurrence wave =================
    v2f wh[H_SZ];                      // {Whh0[j1][k], Whh0[j2][k]} gate-set packed
#pragma unroll
    for (int k = 0; k < H_SZ; ++k) {
      wh[k].x = Whh0[j1 * H_SZ + k]; wh[k].y = Whh0[j2 * H_SZ + k];
    }
    v2f bias2; bias2.x = bih0[j1] + bhh0[j1]; bias2.y = bih0[j2] + bhh0[j2];

    float ha = 0.f, ca = 0.f, hb = 0.f, cb = 0.f;

    for (int s = 0; s <= N_PH + 2; ++s) {
      if (s >= 1 && s <= N_PH) {
        const int p0 = s - 1;
        v2f XsCur = xsbuf[(p0 * P_LEN) & (RING - 1)][l];
        for (int j = 0; j < P_LEN; ++j) {
          const int n = p0 * P_LEN + j;
          const int slot = n & (RING - 1);
          v2f Xs = XsCur;
          if (j + 1 < P_LEN)            // one-step-ahead partial prefetch
            XsCur = xsbuf[(n + 1) & (RING - 1)][l];

          // Recurrent dot, gate-set packed, 2 accs, inline rlane (round-0 form).
          v2f A0 = bias2, A1 = Xs;
#pragma unroll
          for (int k = 0; k < H_SZ; k += 2) {
            float h0 = H_BCAST(ha, hb, k);
            float h1 = H_BCAST(ha, hb, k + 1);
            A0 = fma2(wh[k],     splat2(h0), A0);
            A1 = fma2(wh[k + 1], splat2(h1), A1);
          }
          v2f A = A0 + A1;

          v2f act = act2(A, cm, am, ad);
          float iv = quad_bcast<0>(act.x), fv = quad_bcast<1>(act.x);
          float gv = quad_bcast<2>(act.x), ov = quad_bcast<3>(act.x);
          ca = __fmaf_rn(fv, ca, iv * gv);
          ha = ov * fast_tanh(ca);
          iv = quad_bcast<0>(act.y); fv = quad_bcast<1>(act.y);
          gv = quad_bcast<2>(act.y); ov = quad_bcast<3>(act.y);
          cb = __fmaf_rn(fv, cb, iv * gv);
          hb = ov * fast_tanh(cb);

          if (g == 0) {
            hbuf[slot][k1] = ha;
            if (k1 < 4) hbuf[slot][16 + k1] = hb;
          }
        }
      }
      __syncthreads();
    }
  } else if (wv == 1) {
    // ================= feeder wave (no recurrence chain) =================
    // Computes Xs[phase s] = Wih0 . x  (one phase ahead of L0) and
    //          Ys[phase s-2] = Wih1 . y0 (one phase behind L0, one ahead of L1).
    v2f wx1[C_IN / 2], wx2[C_IN / 2];  // Wih0 rows j1/j2, k-packed
    v2f wy1[H_SZ / 2], wy2[H_SZ / 2];  // Wih1 rows j1/j2, k-packed
#pragma unroll
    for (int t = 0; t < C_IN / 2; ++t) {
      wx1[t].x = Wih0[j1 * C_IN + 2 * t]; wx1[t].y = Wih0[j1 * C_IN + 2 * t + 1];
      wx2[t].x = Wih0[j2 * C_IN + 2 * t]; wx2[t].y = Wih0[j2 * C_IN + 2 * t + 1];
    }
#pragma unroll
    for (int t = 0; t < H_SZ / 2; ++t) {
      wy1[t].x = Wih1[j1 * H_SZ + 2 * t]; wy1[t].y = Wih1[j1 * H_SZ + 2 * t + 1];
      wy2[t].x = Wih1[j2 * H_SZ + 2 * t]; wy2[t].y = Wih1[j2 * H_SZ + 2 * t + 1];
    }

    // Per-lane x slice: element e in [0,128) of a phase -> step e>>3, channel e&7.
    const float* xl = x + (size_t)(l >> 3) * (B_SZ * C_IN) + b * C_IN + (l & 7);
    const size_t halfph = (size_t)8 * B_SZ * C_IN;
    const size_t phstr  = (size_t)P_LEN * B_SZ * C_IN;

    float cur0 = xl[0],     cur1 = xl[halfph];            // phase 0
    float nx0  = xl[phstr], nx1  = xl[phstr + halfph];    // phase 1

    for (int s = 0; s <= N_PH + 2; ++s) {
      // ---- x-dot for phase s (consumed by L0 next superstep) ----
      if (s <= N_PH - 1) {
        xbuf[l] = cur0; xbuf[64 + l] = cur1;
        asm volatile("s_waitcnt lgkmcnt(0)" ::: "memory");
        float4 xc0 = ((const float4*)&xbuf[0])[0];
        float4 xc1 = ((const float4*)&xbuf[0])[1];
        for (int j = 0; j < P_LEN; ++j) {
          v2f xp[4];
          xp[0].x = xc0.x; xp[0].y = xc0.y; xp[1].x = xc0.z; xp[1].y = xc0.w;
          xp[2].x = xc1.x; xp[2].y = xc1.y; xp[3].x = xc1.z; xp[3].y = xc1.w;
          if (j + 1 < P_LEN) {
            xc0 = ((const float4*)&xbuf[(j + 1) * C_IN])[0];
            xc1 = ((const float4*)&xbuf[(j + 1) * C_IN])[1];
          }
          v2f X1 = zero2(), X2 = zero2();
#pragma unroll
          for (int t = 0; t < C_IN / 2; ++t) {
            X1 = fma2(wx1[t], xp[t], X1);
            X2 = fma2(wx2[t], xp[t], X2);
          }
          v2f Xs; Xs.x = X1.x + X1.y; Xs.y = X2.x + X2.y;
          xsbuf[(s * P_LEN + j) & (RING - 1)][l] = Xs;
        }
        cur0 = nx0; cur1 = nx1;
        if (s + 2 <= N_PH - 1) {
          nx0 = xl[(size_t)(s + 2) * phstr];
          nx1 = xl[(size_t)(s + 2) * phstr + halfph];
        }
      }
      // ---- y-dot for phase s-2 (consumed by L1 next superstep) ----
      if (s >= 2 && s <= N_PH + 1) {
        const int q = s - 2;
        for (int j = 0; j < P_LEN; ++j) {
          const int slot = (q * P_LEN + j) & (RING - 1);
          const float4* sp = (const float4*)hbuf[slot];
          float4 y0 = sp[0], y1 = sp[1], y2 = sp[2], y3 = sp[3], y4 = sp[4];
          v2f yp[H_SZ / 2];
          yp[0].x = y0.x; yp[0].y = y0.y; yp[1].x = y0.z; yp[1].y = y0.w;
          yp[2].x = y1.x; yp[2].y = y1.y; yp[3].x = y1.z; yp[3].y = y1.w;
          yp[4].x = y2.x; yp[4].y = y2.y; yp[5].x = y2.z; yp[5].y = y2.w;
          yp[6].x = y3.x; yp[6].y = y3.y; yp[7].x = y3.z; yp[7].y = y3.w;
          yp[8].x = y4.x; yp[8].y = y4.y; yp[9].x = y4.z; yp[9].y = y4.w;

          v2f Y1a = zero2(), Y1b = zero2(), Y2a = zero2(), Y2b = zero2();
#pragma unroll
          for (int t = 0; t < H_SZ / 2; t += 2) {
            Y1a = fma2(wy1[t],     yp[t],     Y1a);
            Y2a = fma2(wy2[t],     yp[t],     Y2a);
            Y1b = fma2(wy1[t + 1], yp[t + 1], Y1b);
            Y2b = fma2(wy2[t + 1], yp[t + 1], Y2b);
          }
          v2f Y1 = Y1a + Y1b, Y2 = Y2a + Y2b;
          v2f Ys; Ys.x = Y1.x + Y1.y; Ys.y = Y2.x + Y2.y;
          ybuf[slot][l] = Ys;
        }
      }
      __syncthreads();
    }
  } else {
    // ================= layer-1 recurrence wave (lags 3 supersteps) =================
    v2f wq[H_SZ];                      // {Whh1[j1][k], Whh1[j2][k]} gate-set packed
#pragma unroll
    for (int k = 0; k < H_SZ; ++k) {
      wq[k].x = Whh1[j1 * H_SZ + k]; wq[k].y = Whh1[j2 * H_SZ + k];
    }
    v2f bias2; bias2.x = bih1[j1] + bhh1[j1]; bias2.y = bih1[j2] + bhh1[j2];

    float ha = 0.f, ca = 0.f, hb = 0.f, cb = 0.f;
    float* op = out + b * H_SZ;

    for (int s = 0; s <= N_PH + 2; ++s) {
      if (s >= 3) {
        const int r = s - 3;
        v2f YsCur = ybuf[(r * P_LEN) & (RING - 1)][l];
        for (int j = 0; j < P_LEN; ++j) {
          const int n = r * P_LEN + j;
          v2f Ys = YsCur;
          if (j + 1 < P_LEN)
            YsCur = ybuf[(n + 1) & (RING - 1)][l];

          v2f Q0 = bias2, Q1 = Ys;
#pragma unroll
          for (int k = 0; k < H_SZ; k += 2) {
            float q0 = H_BCAST(ha, hb, k);
            float q1 = H_BCAST(ha, hb, k + 1);
            Q0 = fma2(wq[k],     splat2(q0), Q0);
            Q1 = fma2(wq[k + 1], splat2(q1), Q1);
          }
          v2f A = Q0 + Q1;

          v2f act = act2(A, cm, am, ad);
          float iv = quad_bcast<0>(act.x), fv = quad_bcast<1>(act.x);
          float gv = quad_bcast<2>(act.x), ov = quad_bcast<3>(act.x);
          ca = __fmaf_rn(fv, ca, iv * gv);
          ha = ov * fast_tanh(ca);
          iv = quad_bcast<0>(act.y); fv = quad_bcast<1>(act.y);
          gv = quad_bcast<2>(act.y); ov = quad_bcast<3>(act.y);
          cb = __fmaf_rn(fv, cb, iv * gv);
          hb = ov * fast_tanh(cb);

          if (g == 0) {
            op[k1] = ha;
            if (k1 < 4) op[16 + k1] = hb;
          }
          op += B_SZ * H_SZ;
        }
      }
      __syncthreads();
    }
  }
}

} // namespace

extern "C" void kernel_launch(void* const* d_in, const int* in_sizes, int n_in,
                              void* d_out, int out_size, void* d_ws, size_t ws_size,
                              hipStream_t stream) {
  const float* x    = (const float*)d_in[0];
  const float* Wih0 = (const float*)d_in[1];
  const float* Whh0 = (const float*)d_in[2];
  const float* bih0 = (const float*)d_in[3];
  const float* bhh0 = (const float*)d_in[4];
  const float* Wih1 = (const float*)d_in[5];
  const float* Whh1 = (const float*)d_in[6];
  const float* bih1 = (const float*)d_in[7];
  const float* bhh1 = (const float*)d_in[8];
  float* out = (float*)d_out;

  hipLaunchKernelGGL(lstm2_3w, dim3(B_SZ), dim3(192), 0, stream,
                     x, Wih0, Whh0, bih0, bhh0, Wih1, Whh1, bih1, bhh1, out);
}

// Round 4
// 916.786 us; speedup vs baseline: 1.1898x; 1.1898x over previous
//
#include <hip/hip_runtime.h>

namespace {

typedef float v2f __attribute__((ext_vector_type(2)));

constexpr int T_SEQ = 2048;
constexpr int B_SZ  = 512;
constexpr int C_IN  = 8;
constexpr int H_SZ  = 20;
constexpr int P_LEN = 16;                 // steps per phase (barrier period)
constexpr int N_PH  = T_SEQ / P_LEN;      // 128 phases
constexpr int RING  = 2 * P_LEN;          // 32-slot rings (2 phases)
constexpr float LOG2E = 1.44269504088896340736f;

__device__ __forceinline__ float rlane(float v, int lane) {
  return __int_as_float(__builtin_amdgcn_readlane(__float_as_int(v), lane));
}

template<int S>
__device__ __forceinline__ float quad_bcast(float v) {
  return __int_as_float(__builtin_amdgcn_update_dpp(
      __float_as_int(v), __float_as_int(v), S * 0x55, 0xF, 0xF, true));
}

__device__ __forceinline__ v2f fma2(v2f a, v2f b, v2f c) {
  return __builtin_elementwise_fma(a, b, c);   // -> v_pk_fma_f32
}
__device__ __forceinline__ v2f splat2(float s) { v2f r; r.x = s; r.y = s; return r; }
__device__ __forceinline__ v2f zero2() { v2f r; r.x = 0.f; r.y = 0.f; return r; }

// Elementwise activation on both gate sets: sigmoid (g!=2) / tanh (g==2).
__device__ __forceinline__ v2f act2(v2f a, float cm, float am, float ad) {
  float ex = __builtin_amdgcn_exp2f(a.x * cm);
  float ey = __builtin_amdgcn_exp2f(a.y * cm);
  float sx = __builtin_amdgcn_rcpf(1.0f + ex);
  float sy = __builtin_amdgcn_rcpf(1.0f + ey);
  v2f r; r.x = __fmaf_rn(sx, am, ad); r.y = __fmaf_rn(sy, am, ad);
  return r;
}

__device__ __forceinline__ float fast_tanh(float a) {
  float e = __builtin_amdgcn_exp2f(a * (-2.0f * LOG2E));
  float s = __builtin_amdgcn_rcpf(1.0f + e);
  return __fmaf_rn(s, 2.0f, -1.0f);
}

// h[k] broadcast from lane-distributed regs (set1 at lanes 4k, k<16;
// set2 value for k=16..19 at lanes 4*(k-16)).  Inline form: rlane result
// feeds pk_fma directly (SGPR fold), no intermediate array.
#define H_BCAST(ha, hb, k) (((k) < 16) ? rlane((ha), 4 * (k)) : rlane((hb), 4 * ((k) - 16)))

__global__ __attribute__((amdgpu_flat_work_group_size(192, 192),
                          amdgpu_waves_per_eu(1, 1)))
void lstm2_3w2b(const float* __restrict__ x,
                const float* __restrict__ Wih0, const float* __restrict__ Whh0,
                const float* __restrict__ bih0, const float* __restrict__ bhh0,
                const float* __restrict__ Wih1, const float* __restrict__ Whh1,
                const float* __restrict__ bih1, const float* __restrict__ bhh1,
                float* __restrict__ out)
{
  // Per-batch rings (index [batch][slot]):
  __shared__ __align__(16) float hbuf[2][RING][H_SZ];   // L0 -> feeder (y0)
  __shared__ __align__(16) v2f   ybuf[2][RING][64];     // feeder -> L1 (y-dot)
  __shared__ __align__(16) v2f   xsbuf[2][RING][64];    // feeder -> L0 (x-dot)
  __shared__ __align__(16) float xbuf[2][P_LEN * C_IN]; // feeder-private x stage

  const int tid = threadIdx.x;
  const int wv  = tid >> 6;          // 0 = layer-0, 1 = feeder, 2 = layer-1
  const int l   = tid & 63;
  const int b0  = blockIdx.x * 2;
  const int b1  = b0 + 1;
  const int k1  = l >> 2;            // 0..15
  const int g   = l & 3;             // gate slot: 0=i 1=f 2=g 3=o
  const int k2  = 16 + (k1 & 3);     // 16..19 (replicated)
  const int j1  = g * H_SZ + k1;
  const int j2  = g * H_SZ + k2;

  const bool  isg = (g == 2);
  const float cm  = isg ? (-2.0f * LOG2E) : (-LOG2E);
  const float am  = isg ?  2.0f : 1.0f;
  const float ad  = isg ? -1.0f : 0.0f;

  if (wv == 0) {
    // ================= layer-0 recurrence wave (2 batches) =================
    v2f wh[H_SZ];                      // {Whh0[j1][k], Whh0[j2][k]} (batch-shared)
#pragma unroll
    for (int k = 0; k < H_SZ; ++k) {
      wh[k].x = Whh0[j1 * H_SZ + k]; wh[k].y = Whh0[j2 * H_SZ + k];
    }
    v2f bias2; bias2.x = bih0[j1] + bhh0[j1]; bias2.y = bih0[j2] + bhh0[j2];

    float ha0 = 0.f, ca0 = 0.f, hb0 = 0.f, cb0 = 0.f;
    float ha1 = 0.f, ca1 = 0.f, hb1 = 0.f, cb1 = 0.f;

    for (int s = 0; s <= N_PH + 2; ++s) {
      if (s >= 1 && s <= N_PH) {
        const int p0 = s - 1;
        v2f Xc0 = xsbuf[0][(p0 * P_LEN) & (RING - 1)][l];
        v2f Xc1 = xsbuf[1][(p0 * P_LEN) & (RING - 1)][l];
        for (int j = 0; j < P_LEN; ++j) {
          const int n = p0 * P_LEN + j;
          const int slot = n & (RING - 1);
          v2f Xs0 = Xc0, Xs1 = Xc1;
          if (j + 1 < P_LEN) {          // one-step-ahead partial prefetch
            Xc0 = xsbuf[0][(n + 1) & (RING - 1)][l];
            Xc1 = xsbuf[1][(n + 1) & (RING - 1)][l];
          }

          // Two independent recurrent dots, interleaved (chains overlap).
          v2f A00 = bias2, A01 = Xs0, A10 = bias2, A11 = Xs1;
#pragma unroll
          for (int k = 0; k < H_SZ; k += 2) {
            float h00 = H_BCAST(ha0, hb0, k);
            float h01 = H_BCAST(ha0, hb0, k + 1);
            float h10 = H_BCAST(ha1, hb1, k);
            float h11 = H_BCAST(ha1, hb1, k + 1);
            A00 = fma2(wh[k],     splat2(h00), A00);
            A01 = fma2(wh[k + 1], splat2(h01), A01);
            A10 = fma2(wh[k],     splat2(h10), A10);
            A11 = fma2(wh[k + 1], splat2(h11), A11);
          }
          v2f A0 = A00 + A01, A1 = A10 + A11;

          // Batch 0 epilogue.
          v2f act0 = act2(A0, cm, am, ad);
          float iv = quad_bcast<0>(act0.x), fv = quad_bcast<1>(act0.x);
          float gv = quad_bcast<2>(act0.x), ov = quad_bcast<3>(act0.x);
          ca0 = __fmaf_rn(fv, ca0, iv * gv);
          ha0 = ov * fast_tanh(ca0);
          iv = quad_bcast<0>(act0.y); fv = quad_bcast<1>(act0.y);
          gv = quad_bcast<2>(act0.y); ov = quad_bcast<3>(act0.y);
          cb0 = __fmaf_rn(fv, cb0, iv * gv);
          hb0 = ov * fast_tanh(cb0);

          // Batch 1 epilogue.
          v2f act1 = act2(A1, cm, am, ad);
          iv = quad_bcast<0>(act1.x); fv = quad_bcast<1>(act1.x);
          gv = quad_bcast<2>(act1.x); ov = quad_bcast<3>(act1.x);
          ca1 = __fmaf_rn(fv, ca1, iv * gv);
          ha1 = ov * fast_tanh(ca1);
          iv = quad_bcast<0>(act1.y); fv = quad_bcast<1>(act1.y);
          gv = quad_bcast<2>(act1.y); ov = quad_bcast<3>(act1.y);
          cb1 = __fmaf_rn(fv, cb1, iv * gv);
          hb1 = ov * fast_tanh(cb1);

          if (g == 0) {
            hbuf[0][slot][k1] = ha0;
            hbuf[1][slot][k1] = ha1;
            if (k1 < 4) {
              hbuf[0][slot][16 + k1] = hb0;
              hbuf[1][slot][16 + k1] = hb1;
            }
          }
        }
      }
      __syncthreads();
    }
  } else if (wv == 1) {
    // ================= feeder wave (no recurrence chain, 2 batches) =========
    v2f wx1[C_IN / 2], wx2[C_IN / 2];  // Wih0 rows j1/j2, k-packed
    v2f wy1[H_SZ / 2], wy2[H_SZ / 2];  // Wih1 rows j1/j2, k-packed
#pragma unroll
    for (int t = 0; t < C_IN / 2; ++t) {
      wx1[t].x = Wih0[j1 * C_IN + 2 * t]; wx1[t].y = Wih0[j1 * C_IN + 2 * t + 1];
      wx2[t].x = Wih0[j2 * C_IN + 2 * t]; wx2[t].y = Wih0[j2 * C_IN + 2 * t + 1];
    }
#pragma unroll
    for (int t = 0; t < H_SZ / 2; ++t) {
      wy1[t].x = Wih1[j1 * H_SZ + 2 * t]; wy1[t].y = Wih1[j1 * H_SZ + 2 * t + 1];
      wy2[t].x = Wih1[j2 * H_SZ + 2 * t]; wy2[t].y = Wih1[j2 * H_SZ + 2 * t + 1];
    }

    // Per-lane x slice: element e in [0,128) of a phase -> step e>>3, channel e&7.
    const float* xl0 = x + (size_t)(l >> 3) * (B_SZ * C_IN) + b0 * C_IN + (l & 7);
    const float* xl1 = x + (size_t)(l >> 3) * (B_SZ * C_IN) + b1 * C_IN + (l & 7);
    const size_t halfph = (size_t)8 * B_SZ * C_IN;
    const size_t phstr  = (size_t)P_LEN * B_SZ * C_IN;

    float c00 = xl0[0], c01 = xl0[halfph];            // batch0, phase 0
    float c10 = xl1[0], c11 = xl1[halfph];            // batch1, phase 0
    float n00 = xl0[phstr], n01 = xl0[phstr + halfph];
    float n10 = xl1[phstr], n11 = xl1[phstr + halfph];

    for (int s = 0; s <= N_PH + 2; ++s) {
      // ---- x-dots for phase s (consumed by L0 next superstep) ----
      if (s <= N_PH - 1) {
        xbuf[0][l] = c00; xbuf[0][64 + l] = c01;
        xbuf[1][l] = c10; xbuf[1][64 + l] = c11;
        asm volatile("s_waitcnt lgkmcnt(0)" ::: "memory");
#pragma unroll 1
        for (int bb = 0; bb < 2; ++bb) {
          float4 xc0 = ((const float4*)&xbuf[bb][0])[0];
          float4 xc1 = ((const float4*)&xbuf[bb][0])[1];
          for (int j = 0; j < P_LEN; ++j) {
            v2f xp[4];
            xp[0].x = xc0.x; xp[0].y = xc0.y; xp[1].x = xc0.z; xp[1].y = xc0.w;
            xp[2].x = xc1.x; xp[2].y = xc1.y; xp[3].x = xc1.z; xp[3].y = xc1.w;
            if (j + 1 < P_LEN) {
              xc0 = ((const float4*)&xbuf[bb][(j + 1) * C_IN])[0];
              xc1 = ((const float4*)&xbuf[bb][(j + 1) * C_IN])[1];
            }
            v2f X1 = zero2(), X2 = zero2();
#pragma unroll
            for (int t = 0; t < C_IN / 2; ++t) {
              X1 = fma2(wx1[t], xp[t], X1);
              X2 = fma2(wx2[t], xp[t], X2);
            }
            v2f Xs; Xs.x = X1.x + X1.y; Xs.y = X2.x + X2.y;
            xsbuf[bb][(s * P_LEN + j) & (RING - 1)][l] = Xs;
          }
        }
        c00 = n00; c01 = n01; c10 = n10; c11 = n11;
        if (s + 2 <= N_PH - 1) {
          n00 = xl0[(size_t)(s + 2) * phstr];
          n01 = xl0[(size_t)(s + 2) * phstr + halfph];
          n10 = xl1[(size_t)(s + 2) * phstr];
          n11 = xl1[(size_t)(s + 2) * phstr + halfph];
        }
      }
      // ---- y-dots for phase s-2 (consumed by L1 next superstep) ----
      if (s >= 2 && s <= N_PH + 1) {
        const int q = s - 2;
#pragma unroll 1
        for (int bb = 0; bb < 2; ++bb) {
          for (int j = 0; j < P_LEN; ++j) {
            const int slot = (q * P_LEN + j) & (RING - 1);
            const float4* sp = (const float4*)hbuf[bb][slot];
            float4 y0 = sp[0], y1 = sp[1], y2 = sp[2], y3 = sp[3], y4 = sp[4];
            v2f yp[H_SZ / 2];
            yp[0].x = y0.x; yp[0].y = y0.y; yp[1].x = y0.z; yp[1].y = y0.w;
            yp[2].x = y1.x; yp[2].y = y1.y; yp[3].x = y1.z; yp[3].y = y1.w;
            yp[4].x = y2.x; yp[4].y = y2.y; yp[5].x = y2.z; yp[5].y = y2.w;
            yp[6].x = y3.x; yp[6].y = y3.y; yp[7].x = y3.z; yp[7].y = y3.w;
            yp[8].x = y4.x; yp[8].y = y4.y; yp[9].x = y4.z; yp[9].y = y4.w;

            v2f Y1a = zero2(), Y1b = zero2(), Y2a = zero2(), Y2b = zero2();
#pragma unroll
            for (int t = 0; t < H_SZ / 2; t += 2) {
              Y1a = fma2(wy1[t],     yp[t],     Y1a);
              Y2a = fma2(wy2[t],     yp[t],     Y2a);
              Y1b = fma2(wy1[t + 1], yp[t + 1], Y1b);
              Y2b = fma2(wy2[t + 1], yp[t + 1], Y2b);
            }
            v2f Y1 = Y1a + Y1b, Y2 = Y2a + Y2b;
            v2f Ys; Ys.x = Y1.x + Y1.y; Ys.y = Y2.x + Y2.y;
            ybuf[bb][slot][l] = Ys;
          }
        }
      }
      __syncthreads();
    }
  } else {
    // ================= layer-1 recurrence wave (2 batches, lags 3) ==========
    v2f wq[H_SZ];                      // {Whh1[j1][k], Whh1[j2][k]} (batch-shared)
#pragma unroll
    for (int k = 0; k < H_SZ; ++k) {
      wq[k].x = Whh1[j1 * H_SZ + k]; wq[k].y = Whh1[j2 * H_SZ + k];
    }
    v2f bias2; bias2.x = bih1[j1] + bhh1[j1]; bias2.y = bih1[j2] + bhh1[j2];

    float ha0 = 0.f, ca0 = 0.f, hb0 = 0.f, cb0 = 0.f;
    float ha1 = 0.f, ca1 = 0.f, hb1 = 0.f, cb1 = 0.f;
    float* op0 = out + b0 * H_SZ;
    float* op1 = out + b1 * H_SZ;

    for (int s = 0; s <= N_PH + 2; ++s) {
      if (s >= 3) {
        const int r = s - 3;
        v2f Yc0 = ybuf[0][(r * P_LEN) & (RING - 1)][l];
        v2f Yc1 = ybuf[1][(r * P_LEN) & (RING - 1)][l];
        for (int j = 0; j < P_LEN; ++j) {
          const int n = r * P_LEN + j;
          v2f Ys0 = Yc0, Ys1 = Yc1;
          if (j + 1 < P_LEN) {
            Yc0 = ybuf[0][(n + 1) & (RING - 1)][l];
            Yc1 = ybuf[1][(n + 1) & (RING - 1)][l];
          }

          v2f Q00 = bias2, Q01 = Ys0, Q10 = bias2, Q11 = Ys1;
#pragma unroll
          for (int k = 0; k < H_SZ; k += 2) {
            float q00 = H_BCAST(ha0, hb0, k);
            float q01 = H_BCAST(ha0, hb0, k + 1);
            float q10 = H_BCAST(ha1, hb1, k);
            float q11 = H_BCAST(ha1, hb1, k + 1);
            Q00 = fma2(wq[k],     splat2(q00), Q00);
            Q01 = fma2(wq[k + 1], splat2(q01), Q01);
            Q10 = fma2(wq[k],     splat2(q10), Q10);
            Q11 = fma2(wq[k + 1], splat2(q11), Q11);
          }
          v2f A0 = Q00 + Q01, A1 = Q10 + Q11;

          // Batch 0 epilogue.
          v2f act0 = act2(A0, cm, am, ad);
          float iv = quad_bcast<0>(act0.x), fv = quad_bcast<1>(act0.x);
          float gv = quad_bcast<2>(act0.x), ov = quad_bcast<3>(act0.x);
          ca0 = __fmaf_rn(fv, ca0, iv * gv);
          ha0 = ov * fast_tanh(ca0);
          iv = quad_bcast<0>(act0.y); fv = quad_bcast<1>(act0.y);
          gv = quad_bcast<2>(act0.y); ov = quad_bcast<3>(act0.y);
          cb0 = __fmaf_rn(fv, cb0, iv * gv);
          hb0 = ov * fast_tanh(cb0);

          // Batch 1 epilogue.
          v2f act1 = act2(A1, cm, am, ad);
          iv = quad_bcast<0>(act1.x); fv = quad_bcast<1>(act1.x);
          gv = quad_bcast<2>(act1.x); ov = quad_bcast<3>(act1.x);
          ca1 = __fmaf_rn(fv, ca1, iv * gv);
          ha1 = ov * fast_tanh(ca1);
          iv = quad_bcast<0>(act1.y); fv = quad_bcast<1>(act1.y);
          gv = quad_bcast<2>(act1.y); ov = quad_bcast<3>(act1.y);
          cb1 = __fmaf_rn(fv, cb1, iv * gv);
          hb1 = ov * fast_tanh(cb1);

          if (g == 0) {
            op0[k1] = ha0;
            op1[k1] = ha1;
            if (k1 < 4) { op0[16 + k1] = hb0; op1[16 + k1] = hb1; }
          }
          op0 += B_SZ * H_SZ;
          op1 += B_SZ * H_SZ;
        }
      }
      __syncthreads();
    }
  }
}

} // namespace

extern "C" void kernel_launch(void* const* d_in, const int* in_sizes, int n_in,
                              void* d_out, int out_size, void* d_ws, size_t ws_size,
                              hipStream_t stream) {
  const float* x    = (const float*)d_in[0];
  const float* Wih0 = (const float*)d_in[1];
  const float* Whh0 = (const float*)d_in[2];
  const float* bih0 = (const float*)d_in[3];
  const float* bhh0 = (const float*)d_in[4];
  const float* Wih1 = (const float*)d_in[5];
  const float* Whh1 = (const float*)d_in[6];
  const float* bih1 = (const float*)d_in[7];
  const float* bhh1 = (const float*)d_in[8];
  float* out = (float*)d_out;

  hipLaunchKernelGGL(lstm2_3w2b, dim3(B_SZ / 2), dim3(192), 0, stream,
                     x, Wih0, Whh0, bih0, bhh0, Wih1, Whh1, bih1, bhh1, out);
}